// Round 4
// baseline (597.889 us; speedup 1.0000x reference)
//
#include <hip/hip_runtime.h>

typedef unsigned short u16;
typedef __attribute__((ext_vector_type(8))) short s16x8;
typedef __attribute__((ext_vector_type(8))) unsigned short u16x8;
typedef __attribute__((ext_vector_type(4))) unsigned short u16x4;
typedef __attribute__((ext_vector_type(4))) float f32x4;

#define DEV __device__ __forceinline__

DEV u16 f2bf(float x) {
  union { float f; unsigned u; } c; c.f = x;
  unsigned r = c.u + 0x7FFFu + ((c.u >> 16) & 1u);
  return (u16)(r >> 16);
}
DEV float bf2f(u16 u) {
  union { unsigned u; float f; } c; c.u = ((unsigned)u) << 16;
  return c.f;
}
DEV void gload_lds16(const void* g, void* l) {
  __builtin_amdgcn_global_load_lds((const __attribute__((address_space(1))) void*)g,
                                   (__attribute__((address_space(3))) void*)l, 16, 0, 0);
}

// ---------------- RMSNorm: f32 [8192][2048] -> bf16 X ----------------
__global__ __launch_bounds__(256) void k_rmsnorm(const float* __restrict__ emb, u16* __restrict__ X) {
  const int row = blockIdx.x;
  const int t = threadIdx.x;
  const float4* p4 = (const float4*)(emb + (size_t)row * 2048);
  float4 v0 = p4[t * 2], v1 = p4[t * 2 + 1];
  float ss = v0.x * v0.x + v0.y * v0.y + v0.z * v0.z + v0.w * v0.w
           + v1.x * v1.x + v1.y * v1.y + v1.z * v1.z + v1.w * v1.w;
  for (int off = 32; off; off >>= 1) ss += __shfl_xor(ss, off);
  __shared__ float red[4];
  if ((t & 63) == 0) red[t >> 6] = ss;
  __syncthreads();
  float tot = red[0] + red[1] + red[2] + red[3];
  float inv = rsqrtf(tot * (1.0f / 2048.0f) + 1e-5f);
  float v[8] = {v0.x, v0.y, v0.z, v0.w, v1.x, v1.y, v1.z, v1.w};
  u16x8 o;
  for (int j = 0; j < 8; ++j) o[j] = f2bf(v[j] * inv);
  *(u16x8*)(X + (size_t)row * 2048 + t * 8) = o;
}

// ------------- transpose f32 [R][C] -> bf16 [C][dstStride] -------------
__global__ __launch_bounds__(256) void k_transpose(const float* __restrict__ src, u16* __restrict__ dst,
                                                   int C, int dstStride) {
  __shared__ float tile[32][33];
  const int bc = blockIdx.x * 32, br = blockIdx.y * 32;
  const int tx = threadIdx.x & 31, ty = threadIdx.x >> 5;
  for (int i = 0; i < 32; i += 8)
    tile[ty + i][tx] = src[(size_t)(br + ty + i) * C + bc + tx];
  __syncthreads();
  for (int i = 0; i < 32; i += 8)
    dst[(size_t)(bc + ty + i) * dstStride + br + tx] = f2bf(tile[tx][ty + i]);
}

// ------------- GEMM C[M][N] = A[M][K] * Bt[N][K]^T  (m97 structure) -------------
// EPI==0: bf16 C write; blocks with n0 >= vcol0 instead write V transposed
//         into VtOut[b][hkv][d][4096] (V needs no RoPE; acc's 4 r-values are
//         4 consecutive s at one d -> one u16x4 store).
// EPI==1: f32 C write + residual add (out-projection epilogue).
template <int EPI>
__global__ __launch_bounds__(256) void k_gemm_bt(const u16* __restrict__ A, const u16* __restrict__ Bt,
                                                 const int N, const int K,
                                                 u16* __restrict__ Cb, const float* __restrict__ Emb,
                                                 float* __restrict__ Cf,
                                                 u16* __restrict__ VtOut, const int vcol0) {
  __shared__ u16 As[128 * 32], Bs[128 * 32];
  const int t = threadIdx.x, w = t >> 6, l = t & 63;
  const int g = l >> 4, cc = l & 15;
  const int wr = w >> 1, wc = w & 1;
  const size_t m0 = (size_t)blockIdx.y * 128, n0 = (size_t)blockIdx.x * 128;
  const int lrow = l >> 2, lcol = (l & 3) * 8;
  f32x4 acc[4][4];
  for (int mi = 0; mi < 4; ++mi)
    for (int ni = 0; ni < 4; ++ni) acc[mi][ni] = (f32x4){0.f, 0.f, 0.f, 0.f};
  for (int k0 = 0; k0 < K; k0 += 32) {
    __syncthreads();
    for (int i = 0; i < 2; ++i) {
      const int ca = w * 2 + i;
      gload_lds16(A + (m0 + ca * 16 + lrow) * K + k0 + lcol, As + ca * 512);
      gload_lds16(Bt + (n0 + ca * 16 + lrow) * K + k0 + lcol, Bs + ca * 512);
    }
    __syncthreads();
    s16x8 a[4], b[4];
    for (int mi = 0; mi < 4; ++mi) a[mi] = *(const s16x8*)&As[(wr * 64 + mi * 16 + cc) * 32 + g * 8];
    for (int ni = 0; ni < 4; ++ni) b[ni] = *(const s16x8*)&Bs[(wc * 64 + ni * 16 + cc) * 32 + g * 8];
    for (int mi = 0; mi < 4; ++mi)
      for (int ni = 0; ni < 4; ++ni)
        acc[mi][ni] = __builtin_amdgcn_mfma_f32_16x16x32_bf16(a[mi], b[ni], acc[mi][ni], 0, 0, 0);
  }
  if (EPI == 1) {
    for (int mi = 0; mi < 4; ++mi)
      for (int ni = 0; ni < 4; ++ni)
        for (int r = 0; r < 4; ++r) {
          const size_t row = m0 + wr * 64 + mi * 16 + g * 4 + r;
          const size_t col = n0 + wc * 64 + ni * 16 + cc;
          Cf[row * N + col] = acc[mi][ni][r] + Emb[row * N + col];
        }
  } else if ((int)n0 >= vcol0) {
    const int hkv = (int)(n0 - vcol0) >> 7;
    const int bb = (int)(m0 >> 12);
    const int s0base = (int)(m0 & 4095);
    u16* vdst = VtOut + (size_t)(bb * 4 + hkv) * 128 * 4096;
    for (int mi = 0; mi < 4; ++mi)
      for (int ni = 0; ni < 4; ++ni) {
        const int d = wc * 64 + ni * 16 + cc;
        const int s = s0base + wr * 64 + mi * 16 + g * 4;
        u16x4 o;
        for (int r = 0; r < 4; ++r) o[r] = f2bf(acc[mi][ni][r]);
        *(u16x4*)(vdst + (size_t)d * 4096 + s) = o;
      }
  } else {
    for (int mi = 0; mi < 4; ++mi)
      for (int ni = 0; ni < 4; ++ni)
        for (int r = 0; r < 4; ++r) {
          const size_t row = m0 + wr * 64 + mi * 16 + g * 4 + r;
          const size_t col = n0 + wc * 64 + ni * 16 + cc;
          Cb[row * N + col] = f2bf(acc[mi][ni][r]);
        }
  }
}

// ------------- RoPE + scatter: qkv [8192][3072] -> Q/K (V handled by GEMM1) -------------
// threads 0..127: Q (16 heads x 8); threads 128..159: K (4 kv heads x 8); 160..191 idle.
__global__ __launch_bounds__(192) void k_rope(const u16* __restrict__ qkv, const float* __restrict__ cosb,
                                              const float* __restrict__ sinb, u16* __restrict__ Q,
                                              u16* __restrict__ K) {
  const int row = blockIdx.x;
  const int b = row >> 12, s = row & 4095;
  const int t = threadIdx.x;
  const u16* src = qkv + (size_t)row * 3072;
  if (t < 128) {
    const int h = t >> 3, d0 = (t & 7) * 8;
    const float* cp = cosb + (size_t)s * 128;
    const float* sp = sinb + (size_t)s * 128;
    u16x8 lo = *(const u16x8*)(src + h * 128 + d0);
    u16x8 hi = *(const u16x8*)(src + h * 128 + d0 + 64);
    u16x8 olo, ohi;
    for (int j = 0; j < 8; ++j) {
      float fl = bf2f(lo[j]), fh = bf2f(hi[j]);
      olo[j] = f2bf(cp[d0 + j] * fl + sp[d0 + j] * fh);
      ohi[j] = f2bf(cp[d0 + 64 + j] * fh + sp[d0 + 64 + j] * fl);
    }
    u16* dq = Q + (((size_t)b * 16 + h) * 4096 + s) * 128;
    *(u16x8*)(dq + d0) = olo;
    *(u16x8*)(dq + d0 + 64) = ohi;
  } else if (t < 160) {   // GUARD: only 4 kv heads (round-3 bug: unguarded else overflowed Kb)
    const int idx = t - 128, hk = idx >> 3, d0 = (idx & 7) * 8;
    const float* cp = cosb + 524288 + (size_t)s * 128;
    const float* sp = sinb + 524288 + (size_t)s * 128;
    u16x8 lo = *(const u16x8*)(src + 2048 + hk * 128 + d0);
    u16x8 hi = *(const u16x8*)(src + 2048 + hk * 128 + d0 + 64);
    u16x8 olo, ohi;
    for (int j = 0; j < 8; ++j) {
      float fl = bf2f(lo[j]), fh = bf2f(hi[j]);
      olo[j] = f2bf(cp[d0 + j] * fl + sp[d0 + j] * fh);
      ohi[j] = f2bf(cp[d0 + 64 + j] * fh + sp[d0 + 64 + j] * fl);
    }
    u16* dk = K + (((size_t)b * 4 + hk) * 4096 + s) * 128;
    *(u16x8*)(dk + d0) = olo;
    *(u16x8*)(dk + d0 + 64) = ohi;
  }
}

// ------------- sliding-window flash attention, barrier-free -------------
// K/V fragments load directly from L1/L2 (per-(b,hkv) K+V = 2 MB, XCD-pinned
// into one 4 MB L2). V is pre-transposed in global (Vt[b][hkv][d][s]) so the
// MFMA B-operand read is natural. Only Ps (wave-private, same-wave) in LDS ->
// no __syncthreads anywhere; waves fully independent.
__global__ __launch_bounds__(256) void k_attn(const u16* __restrict__ Q, const u16* __restrict__ K,
                                              const u16* __restrict__ Vt, u16* __restrict__ AO) {
  const int bid = blockIdx.x;
  const int lin = (bid & 7) * 128 + (bid >> 3);   // XCD-pinned: group = bid&7
  const int grp = lin >> 7;
  const int b = grp >> 2, hkv = grp & 3;
  const int rem = lin & 127;
  const int h = hkv * 4 + (rem >> 5);
  const int qt = rem & 31;

  const int t = threadIdx.x, w = t >> 6, l = t & 63, g = l >> 4, cc = l & 15;
  const int q0 = qt * 128;
  const u16* Qp = Q + (((size_t)b * 16 + h) * 4096 + q0) * 128;
  const u16* Kp = K + ((size_t)b * 4 + hkv) * 4096 * 128;
  const u16* Vp = Vt + ((size_t)b * 4 + hkv) * 128 * 4096;

  __shared__ u16 Ps[4][32 * 72];
  u16* myPs = &Ps[w][0];

  s16x8 qf[2][4];
  for (int mi = 0; mi < 2; ++mi)
    for (int kk = 0; kk < 4; ++kk)
      qf[mi][kk] = *(const s16x8*)(Qp + (size_t)(w * 32 + mi * 16 + cc) * 128 + kk * 32 + g * 8);

  f32x4 accO[2][8];
  for (int mi = 0; mi < 2; ++mi)
    for (int ni = 0; ni < 8; ++ni) accO[mi][ni] = (f32x4){0.f, 0.f, 0.f, 0.f};
  float mrun[2][4], lrun[2][4];
  for (int mi = 0; mi < 2; ++mi)
    for (int r = 0; r < 4; ++r) { mrun[mi][r] = -1e30f; lrun[mi][r] = 0.f; }

  int lo = q0 - 511; if (lo < 0) lo = 0;
  const int kt_lo = lo >> 6, kt_hi = (q0 + 127) >> 6;
  const float scale = 0.08838834764831845f;

  for (int kt = kt_lo; kt <= kt_hi; ++kt) {
    const u16* Ktile = Kp + (size_t)(kt * 64) * 128;

    // S = Q K^T  (K fragments straight from L1/L2)
    f32x4 sc[2][4];
    for (int mi = 0; mi < 2; ++mi)
      for (int ni = 0; ni < 4; ++ni) sc[mi][ni] = (f32x4){0.f, 0.f, 0.f, 0.f};
    __builtin_amdgcn_s_setprio(1);
    for (int kk = 0; kk < 4; ++kk) {
      s16x8 kb[4];
      for (int ni = 0; ni < 4; ++ni)
        kb[ni] = *(const s16x8*)(Ktile + (size_t)(ni * 16 + cc) * 128 + kk * 32 + g * 8);
      for (int mi = 0; mi < 2; ++mi)
        for (int ni = 0; ni < 4; ++ni)
          sc[mi][ni] = __builtin_amdgcn_mfma_f32_16x16x32_bf16(qf[mi][kk], kb[ni], sc[mi][ni], 0, 0, 0);
    }
    __builtin_amdgcn_s_setprio(0);

    const bool full = (kt * 64 >= q0 - 384) && (kt * 64 + 63 <= q0);

    for (int mi = 0; mi < 2; ++mi) {
      if (full) {
        for (int ni = 0; ni < 4; ++ni)
          for (int r = 0; r < 4; ++r) sc[mi][ni][r] *= scale;
      } else {
        for (int ni = 0; ni < 4; ++ni) {
          const int kpos = kt * 64 + ni * 16 + cc;
          for (int r = 0; r < 4; ++r) {
            const int qpos = q0 + w * 32 + mi * 16 + g * 4 + r;
            const float v = sc[mi][ni][r] * scale;
            sc[mi][ni][r] = (kpos <= qpos && kpos + 512 > qpos) ? v : -1e30f;
          }
        }
      }
      for (int r = 0; r < 4; ++r) {
        float rm = fmaxf(fmaxf(sc[mi][0][r], sc[mi][1][r]), fmaxf(sc[mi][2][r], sc[mi][3][r]));
        for (int off = 1; off < 16; off <<= 1) rm = fmaxf(rm, __shfl_xor(rm, off));
        const float mnew = fmaxf(mrun[mi][r], rm);
        float rs = 0.f;
        if (full) {
          for (int ni = 0; ni < 4; ++ni) {
            float pv = __expf(sc[mi][ni][r] - mnew);
            sc[mi][ni][r] = pv;
            rs += pv;
          }
        } else {
          for (int ni = 0; ni < 4; ++ni) {
            float pv = sc[mi][ni][r];
            pv = (pv <= -1e29f) ? 0.f : __expf(pv - mnew);  // guard: mnew may be -1e30
            sc[mi][ni][r] = pv;
            rs += pv;
          }
        }
        for (int off = 1; off < 16; off <<= 1) rs += __shfl_xor(rs, off);
        if (rm > mrun[mi][r]) {   // T13-style: skip rescale when running max unchanged
          const float alpha = __expf(mrun[mi][r] - mnew);
          lrun[mi][r] = lrun[mi][r] * alpha + rs;
          mrun[mi][r] = mnew;
          for (int ni = 0; ni < 8; ++ni) accO[mi][ni][r] *= alpha;
        } else {
          lrun[mi][r] += rs;
        }
      }
      for (int ni = 0; ni < 4; ++ni)
        for (int r = 0; r < 4; ++r)
          myPs[(mi * 16 + g * 4 + r) * 72 + ni * 16 + cc] = f2bf(sc[mi][ni][r]);
    }

    // O += P V  (V^T fragments straight from L1/L2; Ps same-wave, no barrier)
    __builtin_amdgcn_s_setprio(1);
    for (int ks = 0; ks < 2; ++ks) {
      s16x8 pa[2];
      for (int mi = 0; mi < 2; ++mi)
        pa[mi] = *(const s16x8*)&myPs[(mi * 16 + cc) * 72 + ks * 32 + g * 8];
      for (int ni = 0; ni < 8; ++ni) {
        s16x8 vb = *(const s16x8*)(Vp + (size_t)(ni * 16 + cc) * 4096 + kt * 64 + ks * 32 + g * 8);
        for (int mi = 0; mi < 2; ++mi)
          accO[mi][ni] = __builtin_amdgcn_mfma_f32_16x16x32_bf16(pa[mi], vb, accO[mi][ni], 0, 0, 0);
      }
    }
    __builtin_amdgcn_s_setprio(0);
  }

  u16* op = AO + ((size_t)b * 4096 + q0) * 2048 + (size_t)h * 128;
  for (int mi = 0; mi < 2; ++mi)
    for (int ni = 0; ni < 8; ++ni)
      for (int r = 0; r < 4; ++r) {
        const int row = w * 32 + mi * 16 + g * 4 + r;
        op[(size_t)row * 2048 + ni * 16 + cc] = f2bf(accO[mi][ni][r] / lrun[mi][r]);
      }
}

extern "C" void kernel_launch(void* const* d_in, const int* in_sizes, int n_in,
                              void* d_out, int out_size, void* d_ws, size_t ws_size,
                              hipStream_t stream) {
  const float* emb  = (const float*)d_in[0];
  const float* cosb = (const float*)d_in[1];
  const float* sinb = (const float*)d_in[2];
  const float* wq   = (const float*)d_in[3];
  const float* wk   = (const float*)d_in[4];
  const float* wv   = (const float*)d_in[5];
  const float* wo   = (const float*)d_in[6];
  float* out = (float*)d_out;

  char* ws = (char*)d_ws;
  size_t off = 0;
  auto alloc = [&](size_t bytes) -> void* {
    void* p = ws + off;
    off += (bytes + 255) & ~(size_t)255;
    return p;
  };
  u16* X   = (u16*)alloc((size_t)8192 * 2048 * 2);   // normed bf16; reused as attn_out
  u16* Wt  = (u16*)alloc((size_t)3072 * 2048 * 2);   // [wq|wk|wv] transposed [n][k]
  u16* Wot = (u16*)alloc((size_t)2048 * 2048 * 2);   // wo transposed
  u16* qkv = (u16*)alloc((size_t)8192 * 3072 * 2);   // V third unused (V goes to VtB)
  u16* Qb  = (u16*)alloc((size_t)2 * 16 * 4096 * 128 * 2);
  u16* Kb  = (u16*)alloc((size_t)2 * 4 * 4096 * 128 * 2);
  u16* VtB = (u16*)alloc((size_t)2 * 4 * 128 * 4096 * 2);  // V transposed [b][hkv][d][s]
  u16* AOb = X;  // X dead after GEMM1

  k_transpose<<<dim3(64, 64), 256, 0, stream>>>(wq, Wt, 2048, 2048);
  k_transpose<<<dim3(16, 64), 256, 0, stream>>>(wk, Wt + (size_t)2048 * 2048, 512, 2048);
  k_transpose<<<dim3(16, 64), 256, 0, stream>>>(wv, Wt + (size_t)2560 * 2048, 512, 2048);
  k_transpose<<<dim3(64, 64), 256, 0, stream>>>(wo, Wot, 2048, 2048);
  k_rmsnorm<<<8192, 256, 0, stream>>>(emb, X);
  k_gemm_bt<0><<<dim3(24, 64), 256, 0, stream>>>(X, Wt, 3072, 2048, qkv, nullptr, nullptr, VtB, 2560);
  k_rope<<<8192, 192, 0, stream>>>(qkv, cosb, sinb, Qb, Kb);
  k_attn<<<dim3(1024), 256, 0, stream>>>(Qb, Kb, VtB, AOb);
  k_gemm_bt<1><<<dim3(16, 64), 256, 0, stream>>>(AOb, Wot, 2048, 2048, nullptr, emb, out, nullptr, 1 << 30);
}

// Round 5
// 505.675 us; speedup vs baseline: 1.1824x; 1.1824x over previous
//
#include <hip/hip_runtime.h>

typedef unsigned short u16;
typedef __attribute__((ext_vector_type(8))) short s16x8;
typedef __attribute__((ext_vector_type(8))) unsigned short u16x8;
typedef __attribute__((ext_vector_type(4))) unsigned short u16x4;
typedef __attribute__((ext_vector_type(4))) float f32x4;

#define DEV __device__ __forceinline__

DEV u16 f2bf(float x) {
  union { float f; unsigned u; } c; c.f = x;
  unsigned r = c.u + 0x7FFFu + ((c.u >> 16) & 1u);
  return (u16)(r >> 16);
}
DEV float bf2f(u16 u) {
  union { unsigned u; float f; } c; c.u = ((unsigned)u) << 16;
  return c.f;
}
DEV void gload_lds16(const void* g, void* l) {
  __builtin_amdgcn_global_load_lds((const __attribute__((address_space(1))) void*)g,
                                   (__attribute__((address_space(3))) void*)l, 16, 0, 0);
}

// ---------------- RMSNorm: f32 [8192][2048] -> bf16 X ----------------
__global__ __launch_bounds__(256) void k_rmsnorm(const float* __restrict__ emb, u16* __restrict__ X) {
  const int row = blockIdx.x;
  const int t = threadIdx.x;
  const float4* p4 = (const float4*)(emb + (size_t)row * 2048);
  float4 v0 = p4[t * 2], v1 = p4[t * 2 + 1];
  float ss = v0.x * v0.x + v0.y * v0.y + v0.z * v0.z + v0.w * v0.w
           + v1.x * v1.x + v1.y * v1.y + v1.z * v1.z + v1.w * v1.w;
  for (int off = 32; off; off >>= 1) ss += __shfl_xor(ss, off);
  __shared__ float red[4];
  if ((t & 63) == 0) red[t >> 6] = ss;
  __syncthreads();
  float tot = red[0] + red[1] + red[2] + red[3];
  float inv = rsqrtf(tot * (1.0f / 2048.0f) + 1e-5f);
  float v[8] = {v0.x, v0.y, v0.z, v0.w, v1.x, v1.y, v1.z, v1.w};
  u16x8 o;
  for (int j = 0; j < 8; ++j) o[j] = f2bf(v[j] * inv);
  *(u16x8*)(X + (size_t)row * 2048 + t * 8) = o;
}

// ------------- transpose f32 [R][C] -> bf16 [C][dstStride] -------------
__global__ __launch_bounds__(256) void k_transpose(const float* __restrict__ src, u16* __restrict__ dst,
                                                   int C, int dstStride) {
  __shared__ float tile[32][33];
  const int bc = blockIdx.x * 32, br = blockIdx.y * 32;
  const int tx = threadIdx.x & 31, ty = threadIdx.x >> 5;
  for (int i = 0; i < 32; i += 8)
    tile[ty + i][tx] = src[(size_t)(br + ty + i) * C + bc + tx];
  __syncthreads();
  for (int i = 0; i < 32; i += 8)
    dst[(size_t)(bc + ty + i) * dstStride + br + tx] = f2bf(tile[tx][ty + i]);
}

// ------------- GEMM C[M][N] = A[M][K] * Bt[N][K]^T  (m97 structure) -------------
// EPI==0: bf16 C write; blocks with n0 >= vcol0 instead write V transposed
//         into VtOut[b][hkv][d][4096].
// EPI==1: f32 C write + residual add (out-projection epilogue).
template <int EPI>
__global__ __launch_bounds__(256) void k_gemm_bt(const u16* __restrict__ A, const u16* __restrict__ Bt,
                                                 const int N, const int K,
                                                 u16* __restrict__ Cb, const float* __restrict__ Emb,
                                                 float* __restrict__ Cf,
                                                 u16* __restrict__ VtOut, const int vcol0) {
  __shared__ u16 As[128 * 32], Bs[128 * 32];
  const int t = threadIdx.x, w = t >> 6, l = t & 63;
  const int g = l >> 4, cc = l & 15;
  const int wr = w >> 1, wc = w & 1;
  const size_t m0 = (size_t)blockIdx.y * 128, n0 = (size_t)blockIdx.x * 128;
  const int lrow = l >> 2, lcol = (l & 3) * 8;
  f32x4 acc[4][4];
  for (int mi = 0; mi < 4; ++mi)
    for (int ni = 0; ni < 4; ++ni) acc[mi][ni] = (f32x4){0.f, 0.f, 0.f, 0.f};
  for (int k0 = 0; k0 < K; k0 += 32) {
    __syncthreads();
    for (int i = 0; i < 2; ++i) {
      const int ca = w * 2 + i;
      gload_lds16(A + (m0 + ca * 16 + lrow) * K + k0 + lcol, As + ca * 512);
      gload_lds16(Bt + (n0 + ca * 16 + lrow) * K + k0 + lcol, Bs + ca * 512);
    }
    __syncthreads();
    s16x8 a[4], b[4];
    for (int mi = 0; mi < 4; ++mi) a[mi] = *(const s16x8*)&As[(wr * 64 + mi * 16 + cc) * 32 + g * 8];
    for (int ni = 0; ni < 4; ++ni) b[ni] = *(const s16x8*)&Bs[(wc * 64 + ni * 16 + cc) * 32 + g * 8];
    for (int mi = 0; mi < 4; ++mi)
      for (int ni = 0; ni < 4; ++ni)
        acc[mi][ni] = __builtin_amdgcn_mfma_f32_16x16x32_bf16(a[mi], b[ni], acc[mi][ni], 0, 0, 0);
  }
  if (EPI == 1) {
    for (int mi = 0; mi < 4; ++mi)
      for (int ni = 0; ni < 4; ++ni)
        for (int r = 0; r < 4; ++r) {
          const size_t row = m0 + wr * 64 + mi * 16 + g * 4 + r;
          const size_t col = n0 + wc * 64 + ni * 16 + cc;
          Cf[row * N + col] = acc[mi][ni][r] + Emb[row * N + col];
        }
  } else if ((int)n0 >= vcol0) {
    const int hkv = (int)(n0 - vcol0) >> 7;
    const int bb = (int)(m0 >> 12);
    const int s0base = (int)(m0 & 4095);
    u16* vdst = VtOut + (size_t)(bb * 4 + hkv) * 128 * 4096;
    for (int mi = 0; mi < 4; ++mi)
      for (int ni = 0; ni < 4; ++ni) {
        const int d = wc * 64 + ni * 16 + cc;
        const int s = s0base + wr * 64 + mi * 16 + g * 4;
        u16x4 o;
        for (int r = 0; r < 4; ++r) o[r] = f2bf(acc[mi][ni][r]);
        *(u16x4*)(vdst + (size_t)d * 4096 + s) = o;
      }
  } else {
    for (int mi = 0; mi < 4; ++mi)
      for (int ni = 0; ni < 4; ++ni)
        for (int r = 0; r < 4; ++r) {
          const size_t row = m0 + wr * 64 + mi * 16 + g * 4 + r;
          const size_t col = n0 + wc * 64 + ni * 16 + cc;
          Cb[row * N + col] = f2bf(acc[mi][ni][r]);
        }
  }
}

// ------------- RoPE + scatter: qkv [8192][3072] -> Q/K (V handled by GEMM1) -------------
__global__ __launch_bounds__(192) void k_rope(const u16* __restrict__ qkv, const float* __restrict__ cosb,
                                              const float* __restrict__ sinb, u16* __restrict__ Q,
                                              u16* __restrict__ K) {
  const int row = blockIdx.x;
  const int b = row >> 12, s = row & 4095;
  const int t = threadIdx.x;
  const u16* src = qkv + (size_t)row * 3072;
  if (t < 128) {
    const int h = t >> 3, d0 = (t & 7) * 8;
    const float* cp = cosb + (size_t)s * 128;
    const float* sp = sinb + (size_t)s * 128;
    u16x8 lo = *(const u16x8*)(src + h * 128 + d0);
    u16x8 hi = *(const u16x8*)(src + h * 128 + d0 + 64);
    u16x8 olo, ohi;
    for (int j = 0; j < 8; ++j) {
      float fl = bf2f(lo[j]), fh = bf2f(hi[j]);
      olo[j] = f2bf(cp[d0 + j] * fl + sp[d0 + j] * fh);
      ohi[j] = f2bf(cp[d0 + 64 + j] * fh + sp[d0 + 64 + j] * fl);
    }
    u16* dq = Q + (((size_t)b * 16 + h) * 4096 + s) * 128;
    *(u16x8*)(dq + d0) = olo;
    *(u16x8*)(dq + d0 + 64) = ohi;
  } else if (t < 160) {   // only 4 kv heads
    const int idx = t - 128, hk = idx >> 3, d0 = (idx & 7) * 8;
    const float* cp = cosb + 524288 + (size_t)s * 128;
    const float* sp = sinb + 524288 + (size_t)s * 128;
    u16x8 lo = *(const u16x8*)(src + 2048 + hk * 128 + d0);
    u16x8 hi = *(const u16x8*)(src + 2048 + hk * 128 + d0 + 64);
    u16x8 olo, ohi;
    for (int j = 0; j < 8; ++j) {
      float fl = bf2f(lo[j]), fh = bf2f(hi[j]);
      olo[j] = f2bf(cp[d0 + j] * fl + sp[d0 + j] * fh);
      ohi[j] = f2bf(cp[d0 + 64 + j] * fh + sp[d0 + 64 + j] * fl);
    }
    u16* dk = K + (((size_t)b * 4 + hk) * 4096 + s) * 128;
    *(u16x8*)(dk + d0) = olo;
    *(u16x8*)(dk + d0 + 64) = ohi;
  }
}

// ------------- sliding-window flash attention, swapped-operand (lane-local softmax) -------------
// QK^T computed as mfma(K,Q): score col=cc<->q, row=g*4+r<->k  => each lane owns one
// q-row's 16 scores in registers; 64-key reduce = 15 reg ops + 2 shfl (was 8 shfl chains).
// PV computed as mfma(V,P): accO col=cc<->q => m/l/alpha state fully lane-local.
// K/Vt fragments straight from L1/L2 (per-(b,hkv) K+V = 2 MB, XCD-pinned). No barriers.
__global__ __launch_bounds__(256) void k_attn(const u16* __restrict__ Q, const u16* __restrict__ K,
                                              const u16* __restrict__ Vt, u16* __restrict__ AO) {
  const int bid = blockIdx.x;
  const int lin = (bid & 7) * 128 + (bid >> 3);   // XCD-pinned: group = bid&7
  const int grp = lin >> 7;
  const int b = grp >> 2, hkv = grp & 3;
  const int rem = lin & 127;
  const int h = hkv * 4 + (rem >> 5);
  const int qt = rem & 31;

  const int t = threadIdx.x, w = t >> 6, l = t & 63, g = l >> 4, cc = l & 15;
  const int q0 = qt * 128;
  const u16* Qp = Q + (((size_t)b * 16 + h) * 4096 + q0) * 128;
  const u16* Kp = K + ((size_t)b * 4 + hkv) * 4096 * 128;
  const u16* Vp = Vt + ((size_t)b * 4 + hkv) * 128 * 4096;

  __shared__ u16 Ps[4][32 * 72];
  u16* myPs = &Ps[w][0];

  s16x8 qf[2][4];
  for (int mi = 0; mi < 2; ++mi)
    for (int kk = 0; kk < 4; ++kk)
      qf[mi][kk] = *(const s16x8*)(Qp + (size_t)(w * 32 + mi * 16 + cc) * 128 + kk * 32 + g * 8);

  f32x4 accO[2][8];
  for (int mi = 0; mi < 2; ++mi)
    for (int nd = 0; nd < 8; ++nd) accO[mi][nd] = (f32x4){0.f, 0.f, 0.f, 0.f};
  float mrun[2], lrun[2];
  for (int mi = 0; mi < 2; ++mi) { mrun[mi] = -1e30f; lrun[mi] = 0.f; }

  int lo = q0 - 511; if (lo < 0) lo = 0;
  const int kt_lo = lo >> 6, kt_hi = (q0 + 127) >> 6;
  const float scale = 0.08838834764831845f;

  for (int kt = kt_lo; kt <= kt_hi; ++kt) {
    const u16* Ktile = Kp + (size_t)(kt * 64) * 128;

    // S^T tile: sc[mi][nk], col=cc (q within mi-tile), row=g*4+r (k within nk-tile)
    f32x4 sc[2][4];
    for (int mi = 0; mi < 2; ++mi)
      for (int nk = 0; nk < 4; ++nk) sc[mi][nk] = (f32x4){0.f, 0.f, 0.f, 0.f};
    __builtin_amdgcn_s_setprio(1);
    for (int kk = 0; kk < 4; ++kk) {
      s16x8 kb[4];
      for (int nk = 0; nk < 4; ++nk)
        kb[nk] = *(const s16x8*)(Ktile + (size_t)(nk * 16 + cc) * 128 + kk * 32 + g * 8);
      for (int mi = 0; mi < 2; ++mi)
        for (int nk = 0; nk < 4; ++nk)
          sc[mi][nk] = __builtin_amdgcn_mfma_f32_16x16x32_bf16(kb[nk], qf[mi][kk], sc[mi][nk], 0, 0, 0);
    }
    __builtin_amdgcn_s_setprio(0);

    const bool full = (kt * 64 >= q0 - 384) && (kt * 64 + 63 <= q0);

    for (int mi = 0; mi < 2; ++mi) {
      const int qpos = q0 + w * 32 + mi * 16 + cc;
      if (full) {
        for (int nk = 0; nk < 4; ++nk)
          for (int r = 0; r < 4; ++r) sc[mi][nk][r] *= scale;
      } else {
        for (int nk = 0; nk < 4; ++nk)
          for (int r = 0; r < 4; ++r) {
            const int kpos = kt * 64 + nk * 16 + g * 4 + r;
            const float v = sc[mi][nk][r] * scale;
            sc[mi][nk][r] = (kpos <= qpos && kpos + 512 > qpos) ? v : -1e30f;
          }
      }
      // lane-local row reduce (q = cc): 15 reg max + 2 shfl across the 4 g-replicas
      float rm = sc[mi][0][0];
      for (int nk = 0; nk < 4; ++nk)
        for (int r = 0; r < 4; ++r) rm = fmaxf(rm, sc[mi][nk][r]);
      rm = fmaxf(rm, __shfl_xor(rm, 16));
      rm = fmaxf(rm, __shfl_xor(rm, 32));
      const float mnew = fmaxf(mrun[mi], rm);
      float rs = 0.f;
      if (full) {
        for (int nk = 0; nk < 4; ++nk)
          for (int r = 0; r < 4; ++r) {
            float pv = __expf(sc[mi][nk][r] - mnew);
            sc[mi][nk][r] = pv;
            rs += pv;
          }
      } else {
        for (int nk = 0; nk < 4; ++nk)
          for (int r = 0; r < 4; ++r) {
            float pv = sc[mi][nk][r];
            pv = (pv <= -1e29f) ? 0.f : __expf(pv - mnew);  // guard: mnew may be -1e30
            sc[mi][nk][r] = pv;
            rs += pv;
          }
      }
      rs += __shfl_xor(rs, 16);
      rs += __shfl_xor(rs, 32);
      const float alpha = __expf(mrun[mi] - mnew);  // exp(0)=1 when max unchanged
      mrun[mi] = mnew;
      lrun[mi] = lrun[mi] * alpha + rs;
      for (int nd = 0; nd < 8; ++nd)
        for (int r = 0; r < 4; ++r) accO[mi][nd][r] *= alpha;
      // Ps write: P[q=mi*16+cc][k=nk*16+g*4+r] -> one u16x4 per nk
      for (int nk = 0; nk < 4; ++nk) {
        u16x4 o;
        for (int r = 0; r < 4; ++r) o[r] = f2bf(sc[mi][nk][r]);
        *(u16x4*)&myPs[(mi * 16 + cc) * 72 + nk * 16 + g * 4] = o;
      }
    }

    // O^T += V^T P^T : accO[mi][nd], col=cc (q), row=g*4+r (d within nd-tile)
    __builtin_amdgcn_s_setprio(1);
    for (int ks = 0; ks < 2; ++ks) {
      s16x8 pa[2];
      for (int mi = 0; mi < 2; ++mi)
        pa[mi] = *(const s16x8*)&myPs[(mi * 16 + cc) * 72 + ks * 32 + g * 8];
      for (int nd = 0; nd < 8; ++nd) {
        s16x8 vb = *(const s16x8*)(Vp + (size_t)(nd * 16 + cc) * 4096 + kt * 64 + ks * 32 + g * 8);
        for (int mi = 0; mi < 2; ++mi)
          accO[mi][nd] = __builtin_amdgcn_mfma_f32_16x16x32_bf16(vb, pa[mi], accO[mi][nd], 0, 0, 0);
      }
    }
    __builtin_amdgcn_s_setprio(0);
  }

  // write O: q = w*32+mi*16+cc (row), d = nd*16+g*4+r (col) -> u16x4 stores
  u16* op = AO + ((size_t)b * 4096 + q0) * 2048 + (size_t)h * 128;
  for (int mi = 0; mi < 2; ++mi) {
    const float inv = 1.0f / lrun[mi];
    for (int nd = 0; nd < 8; ++nd) {
      u16x4 o;
      for (int r = 0; r < 4; ++r) o[r] = f2bf(accO[mi][nd][r] * inv);
      *(u16x4*)(op + (size_t)(w * 32 + mi * 16 + cc) * 2048 + nd * 16 + g * 4) = o;
    }
  }
}

extern "C" void kernel_launch(void* const* d_in, const int* in_sizes, int n_in,
                              void* d_out, int out_size, void* d_ws, size_t ws_size,
                              hipStream_t stream) {
  const float* emb  = (const float*)d_in[0];
  const float* cosb = (const float*)d_in[1];
  const float* sinb = (const float*)d_in[2];
  const float* wq   = (const float*)d_in[3];
  const float* wk   = (const float*)d_in[4];
  const float* wv   = (const float*)d_in[5];
  const float* wo   = (const float*)d_in[6];
  float* out = (float*)d_out;

  char* ws = (char*)d_ws;
  size_t off = 0;
  auto alloc = [&](size_t bytes) -> void* {
    void* p = ws + off;
    off += (bytes + 255) & ~(size_t)255;
    return p;
  };
  u16* X   = (u16*)alloc((size_t)8192 * 2048 * 2);   // normed bf16; reused as attn_out
  u16* Wt  = (u16*)alloc((size_t)3072 * 2048 * 2);   // [wq|wk|wv] transposed [n][k]
  u16* Wot = (u16*)alloc((size_t)2048 * 2048 * 2);   // wo transposed
  u16* qkv = (u16*)alloc((size_t)8192 * 3072 * 2);   // V third unused (V goes to VtB)
  u16* Qb  = (u16*)alloc((size_t)2 * 16 * 4096 * 128 * 2);
  u16* Kb  = (u16*)alloc((size_t)2 * 4 * 4096 * 128 * 2);
  u16* VtB = (u16*)alloc((size_t)2 * 4 * 128 * 4096 * 2);  // V transposed [b][hkv][d][s]
  u16* AOb = X;  // X dead after GEMM1

  k_transpose<<<dim3(64, 64), 256, 0, stream>>>(wq, Wt, 2048, 2048);
  k_transpose<<<dim3(16, 64), 256, 0, stream>>>(wk, Wt + (size_t)2048 * 2048, 512, 2048);
  k_transpose<<<dim3(16, 64), 256, 0, stream>>>(wv, Wt + (size_t)2560 * 2048, 512, 2048);
  k_transpose<<<dim3(64, 64), 256, 0, stream>>>(wo, Wot, 2048, 2048);
  k_rmsnorm<<<8192, 256, 0, stream>>>(emb, X);
  k_gemm_bt<0><<<dim3(24, 64), 256, 0, stream>>>(X, Wt, 3072, 2048, qkv, nullptr, nullptr, VtB, 2560);
  k_rope<<<8192, 192, 0, stream>>>(qkv, cosb, sinb, Qb, Kb);
  k_attn<<<dim3(1024), 256, 0, stream>>>(Qb, Kb, VtB, AOb);
  k_gemm_bt<1><<<dim3(16, 64), 256, 0, stream>>>(AOb, Wot, 2048, 2048, nullptr, emb, out, nullptr, 1 << 30);
}

// Round 6
// 408.844 us; speedup vs baseline: 1.4624x; 1.2368x over previous
//
#include <hip/hip_runtime.h>

typedef unsigned short u16;
typedef __attribute__((ext_vector_type(8))) short s16x8;
typedef __attribute__((ext_vector_type(8))) unsigned short u16x8;
typedef __attribute__((ext_vector_type(4))) unsigned short u16x4;
typedef __attribute__((ext_vector_type(4))) float f32x4;

#define DEV __device__ __forceinline__

DEV u16 f2bf(float x) {
  union { float f; unsigned u; } c; c.f = x;
  unsigned r = c.u + 0x7FFFu + ((c.u >> 16) & 1u);
  return (u16)(r >> 16);
}
DEV float bf2f(u16 u) {
  union { unsigned u; float f; } c; c.u = ((unsigned)u) << 16;
  return c.f;
}
DEV void gload_lds16(const void* g, void* l) {
  __builtin_amdgcn_global_load_lds((const __attribute__((address_space(1))) void*)g,
                                   (__attribute__((address_space(3))) void*)l, 16, 0, 0);
}

// ---------------- RMSNorm: f32 [8192][2048] -> bf16 X ----------------
__global__ __launch_bounds__(256) void k_rmsnorm(const float* __restrict__ emb, u16* __restrict__ X) {
  const int row = blockIdx.x;
  const int t = threadIdx.x;
  const float4* p4 = (const float4*)(emb + (size_t)row * 2048);
  float4 v0 = p4[t * 2], v1 = p4[t * 2 + 1];
  float ss = v0.x * v0.x + v0.y * v0.y + v0.z * v0.z + v0.w * v0.w
           + v1.x * v1.x + v1.y * v1.y + v1.z * v1.z + v1.w * v1.w;
  for (int off = 32; off; off >>= 1) ss += __shfl_xor(ss, off);
  __shared__ float red[4];
  if ((t & 63) == 0) red[t >> 6] = ss;
  __syncthreads();
  float tot = red[0] + red[1] + red[2] + red[3];
  float inv = rsqrtf(tot * (1.0f / 2048.0f) + 1e-5f);
  float v[8] = {v0.x, v0.y, v0.z, v0.w, v1.x, v1.y, v1.z, v1.w};
  u16x8 o;
  for (int j = 0; j < 8; ++j) o[j] = f2bf(v[j] * inv);
  *(u16x8*)(X + (size_t)row * 2048 + t * 8) = o;
}

// ------------- transpose f32 [R][C] -> bf16 [C][dstStride] -------------
__global__ __launch_bounds__(256) void k_transpose(const float* __restrict__ src, u16* __restrict__ dst,
                                                   int C, int dstStride) {
  __shared__ float tile[32][33];
  const int bc = blockIdx.x * 32, br = blockIdx.y * 32;
  const int tx = threadIdx.x & 31, ty = threadIdx.x >> 5;
  for (int i = 0; i < 32; i += 8)
    tile[ty + i][tx] = src[(size_t)(br + ty + i) * C + bc + tx];
  __syncthreads();
  for (int i = 0; i < 32; i += 8)
    dst[(size_t)(bc + ty + i) * dstStride + br + tx] = f2bf(tile[tx][ty + i]);
}

// ------------- GEMM C[M][N] = A[M][K] * Bt[N][K]^T  (m97 structure) -------------
template <int EPI>
__global__ __launch_bounds__(256) void k_gemm_bt(const u16* __restrict__ A, const u16* __restrict__ Bt,
                                                 const int N, const int K,
                                                 u16* __restrict__ Cb, const float* __restrict__ Emb,
                                                 float* __restrict__ Cf,
                                                 u16* __restrict__ VtOut, const int vcol0) {
  __shared__ u16 As[128 * 32], Bs[128 * 32];
  const int t = threadIdx.x, w = t >> 6, l = t & 63;
  const int g = l >> 4, cc = l & 15;
  const int wr = w >> 1, wc = w & 1;
  const size_t m0 = (size_t)blockIdx.y * 128, n0 = (size_t)blockIdx.x * 128;
  const int lrow = l >> 2, lcol = (l & 3) * 8;
  f32x4 acc[4][4];
  for (int mi = 0; mi < 4; ++mi)
    for (int ni = 0; ni < 4; ++ni) acc[mi][ni] = (f32x4){0.f, 0.f, 0.f, 0.f};
  for (int k0 = 0; k0 < K; k0 += 32) {
    __syncthreads();
    for (int i = 0; i < 2; ++i) {
      const int ca = w * 2 + i;
      gload_lds16(A + (m0 + ca * 16 + lrow) * K + k0 + lcol, As + ca * 512);
      gload_lds16(Bt + (n0 + ca * 16 + lrow) * K + k0 + lcol, Bs + ca * 512);
    }
    __syncthreads();
    s16x8 a[4], b[4];
    for (int mi = 0; mi < 4; ++mi) a[mi] = *(const s16x8*)&As[(wr * 64 + mi * 16 + cc) * 32 + g * 8];
    for (int ni = 0; ni < 4; ++ni) b[ni] = *(const s16x8*)&Bs[(wc * 64 + ni * 16 + cc) * 32 + g * 8];
    for (int mi = 0; mi < 4; ++mi)
      for (int ni = 0; ni < 4; ++ni)
        acc[mi][ni] = __builtin_amdgcn_mfma_f32_16x16x32_bf16(a[mi], b[ni], acc[mi][ni], 0, 0, 0);
  }
  if (EPI == 1) {
    for (int mi = 0; mi < 4; ++mi)
      for (int ni = 0; ni < 4; ++ni)
        for (int r = 0; r < 4; ++r) {
          const size_t row = m0 + wr * 64 + mi * 16 + g * 4 + r;
          const size_t col = n0 + wc * 64 + ni * 16 + cc;
          Cf[row * N + col] = acc[mi][ni][r] + Emb[row * N + col];
        }
  } else if ((int)n0 >= vcol0) {
    const int hkv = (int)(n0 - vcol0) >> 7;
    const int bb = (int)(m0 >> 12);
    const int s0base = (int)(m0 & 4095);
    u16* vdst = VtOut + (size_t)(bb * 4 + hkv) * 128 * 4096;
    for (int mi = 0; mi < 4; ++mi)
      for (int ni = 0; ni < 4; ++ni) {
        const int d = wc * 64 + ni * 16 + cc;
        const int s = s0base + wr * 64 + mi * 16 + g * 4;
        u16x4 o;
        for (int r = 0; r < 4; ++r) o[r] = f2bf(acc[mi][ni][r]);
        *(u16x4*)(vdst + (size_t)d * 4096 + s) = o;
      }
  } else {
    for (int mi = 0; mi < 4; ++mi)
      for (int ni = 0; ni < 4; ++ni)
        for (int r = 0; r < 4; ++r) {
          const size_t row = m0 + wr * 64 + mi * 16 + g * 4 + r;
          const size_t col = n0 + wc * 64 + ni * 16 + cc;
          Cb[row * N + col] = f2bf(acc[mi][ni][r]);
        }
  }
}

// ------------- RoPE + scatter: qkv [8192][3072] -> Q/K (V handled by GEMM1) -------------
__global__ __launch_bounds__(192) void k_rope(const u16* __restrict__ qkv, const float* __restrict__ cosb,
                                              const float* __restrict__ sinb, u16* __restrict__ Q,
                                              u16* __restrict__ K) {
  const int row = blockIdx.x;
  const int b = row >> 12, s = row & 4095;
  const int t = threadIdx.x;
  const u16* src = qkv + (size_t)row * 3072;
  if (t < 128) {
    const int h = t >> 3, d0 = (t & 7) * 8;
    const float* cp = cosb + (size_t)s * 128;
    const float* sp = sinb + (size_t)s * 128;
    u16x8 lo = *(const u16x8*)(src + h * 128 + d0);
    u16x8 hi = *(const u16x8*)(src + h * 128 + d0 + 64);
    u16x8 olo, ohi;
    for (int j = 0; j < 8; ++j) {
      float fl = bf2f(lo[j]), fh = bf2f(hi[j]);
      olo[j] = f2bf(cp[d0 + j] * fl + sp[d0 + j] * fh);
      ohi[j] = f2bf(cp[d0 + 64 + j] * fh + sp[d0 + 64 + j] * fl);
    }
    u16* dq = Q + (((size_t)b * 16 + h) * 4096 + s) * 128;
    *(u16x8*)(dq + d0) = olo;
    *(u16x8*)(dq + d0 + 64) = ohi;
  } else if (t < 160) {   // only 4 kv heads
    const int idx = t - 128, hk = idx >> 3, d0 = (idx & 7) * 8;
    const float* cp = cosb + 524288 + (size_t)s * 128;
    const float* sp = sinb + 524288 + (size_t)s * 128;
    u16x8 lo = *(const u16x8*)(src + 2048 + hk * 128 + d0);
    u16x8 hi = *(const u16x8*)(src + 2048 + hk * 128 + d0 + 64);
    u16x8 olo, ohi;
    for (int j = 0; j < 8; ++j) {
      float fl = bf2f(lo[j]), fh = bf2f(hi[j]);
      olo[j] = f2bf(cp[d0 + j] * fl + sp[d0 + j] * fh);
      ohi[j] = f2bf(cp[d0 + 64 + j] * fh + sp[d0 + 64 + j] * fl);
    }
    u16* dk = K + (((size_t)b * 4 + hk) * 4096 + s) * 128;
    *(u16x8*)(dk + d0) = olo;
    *(u16x8*)(dk + d0 + 64) = ohi;
  }
}

// ------------- sliding-window flash attention, 2-phase pipelined LDS staging -------------
// R5's lane-local softmax (swapped MFMA operands) + coalesced global_load_lds staging of
// K and V (fixes the scattered-gather L1-miss wall of R4/R5) + T3-minimum pipeline:
// STAGE(next tile) issued BEFORE compute(current), ONE __syncthreads per tile (its
// vmcnt(0) drain lands after compute, so load latency hides under MFMA/softmax).
// KVBLK=32, double-buffered. Both-sides XOR swizzle: K rows 256B (16 chunks, ^row&7 ->
// conflict-free), V rows 64B (4 chunks, ^d&3 -> 4-way max, acceptable).
__global__ __launch_bounds__(256) void k_attn(const u16* __restrict__ Q, const u16* __restrict__ K,
                                              const u16* __restrict__ Vt, u16* __restrict__ AO) {
  const int bid = blockIdx.x;
  const int lin = (bid & 7) * 128 + (bid >> 3);   // XCD-pinned: group = bid&7
  const int grp = lin >> 7;
  const int b = grp >> 2, hkv = grp & 3;
  const int rem = lin & 127;
  const int h = hkv * 4 + (rem >> 5);
  const int qt = rem & 31;

  const int t = threadIdx.x, w = t >> 6, l = t & 63, g = l >> 4, cc = l & 15;
  const int q0 = qt * 128;
  const u16* Qp = Q + (((size_t)b * 16 + h) * 4096 + q0) * 128;
  const u16* Kp = K + ((size_t)b * 4 + hkv) * 4096 * 128;
  const u16* Vp = Vt + ((size_t)b * 4 + hkv) * 128 * 4096;

  __shared__ u16 Kl[2][32 * 128];   // [key][d], swizzled chunks (^row&7)
  __shared__ u16 Vl[2][128 * 32];   // [d][key], swizzled chunks (^d&3)
  __shared__ u16 Ps[4][32 * 40];    // per-wave P, stride 40 u16 (16B-aligned rows)
  u16* myPs = &Ps[w][0];

  // stage one 32-key tile (K: 8KB, V: 8KB) with inverse-swizzled global source
  auto stage = [&](int kt, int bufi) {
    for (int pass = 0; pass < 2; ++pass) {
      const int m = pass * 256 + t;
      const int row = m >> 4, cst = m & 15;
      const int cor = cst ^ (row & 7);
      gload_lds16(Kp + (size_t)(kt * 32 + row) * 128 + cor * 8, &Kl[bufi][m * 8]);
    }
    for (int pass = 0; pass < 2; ++pass) {
      const int m = pass * 256 + t;
      const int d = m >> 2, cst = m & 3;
      const int cor = cst ^ (d & 3);
      gload_lds16(Vp + (size_t)d * 4096 + kt * 32 + cor * 8, &Vl[bufi][m * 8]);
    }
  };

  s16x8 qf[2][4];
  for (int mi = 0; mi < 2; ++mi)
    for (int kk = 0; kk < 4; ++kk)
      qf[mi][kk] = *(const s16x8*)(Qp + (size_t)(w * 32 + mi * 16 + cc) * 128 + kk * 32 + g * 8);

  f32x4 accO[2][8];
  for (int mi = 0; mi < 2; ++mi)
    for (int nd = 0; nd < 8; ++nd) accO[mi][nd] = (f32x4){0.f, 0.f, 0.f, 0.f};
  float mrun[2], lrun[2];
  for (int mi = 0; mi < 2; ++mi) { mrun[mi] = -1e30f; lrun[mi] = 0.f; }

  int lo = q0 - 511; if (lo < 0) lo = 0;
  const int kt_lo = lo >> 5, kt_hi = (q0 + 127) >> 5;
  const float scale = 0.08838834764831845f;

  int cur = 0;
  stage(kt_lo, 0);
  __syncthreads();

  for (int kt = kt_lo; kt <= kt_hi; ++kt) {
    if (kt < kt_hi) stage(kt + 1, cur ^ 1);   // in flight during compute below

    // S^T: sc[mi][nk], col=cc (q), row=g*4+r (k)
    f32x4 sc[2][2];
    for (int mi = 0; mi < 2; ++mi)
      for (int nk = 0; nk < 2; ++nk) sc[mi][nk] = (f32x4){0.f, 0.f, 0.f, 0.f};
    __builtin_amdgcn_s_setprio(1);
    for (int kk = 0; kk < 4; ++kk) {
      s16x8 kb[2];
      for (int nk = 0; nk < 2; ++nk) {
        const int row = nk * 16 + cc;
        kb[nk] = *(const s16x8*)&Kl[cur][row * 128 + (((kk * 4 + g) ^ (row & 7)) * 8)];
      }
      for (int mi = 0; mi < 2; ++mi)
        for (int nk = 0; nk < 2; ++nk)
          sc[mi][nk] = __builtin_amdgcn_mfma_f32_16x16x32_bf16(kb[nk], qf[mi][kk], sc[mi][nk], 0, 0, 0);
    }
    __builtin_amdgcn_s_setprio(0);

    const bool full = (kt * 32 >= q0 - 384) && (kt * 32 + 31 <= q0);

    for (int mi = 0; mi < 2; ++mi) {
      const int qpos = q0 + w * 32 + mi * 16 + cc;
      if (full) {
        for (int nk = 0; nk < 2; ++nk)
          for (int r = 0; r < 4; ++r) sc[mi][nk][r] *= scale;
      } else {
        for (int nk = 0; nk < 2; ++nk)
          for (int r = 0; r < 4; ++r) {
            const int kpos = kt * 32 + nk * 16 + g * 4 + r;
            const float v = sc[mi][nk][r] * scale;
            sc[mi][nk][r] = (kpos <= qpos && kpos + 512 > qpos) ? v : -1e30f;
          }
      }
      float rm = sc[mi][0][0];
      for (int nk = 0; nk < 2; ++nk)
        for (int r = 0; r < 4; ++r) rm = fmaxf(rm, sc[mi][nk][r]);
      rm = fmaxf(rm, __shfl_xor(rm, 16));
      rm = fmaxf(rm, __shfl_xor(rm, 32));
      const float mnew = fmaxf(mrun[mi], rm);
      float rs = 0.f;
      if (full) {
        for (int nk = 0; nk < 2; ++nk)
          for (int r = 0; r < 4; ++r) {
            float pv = __expf(sc[mi][nk][r] - mnew);
            sc[mi][nk][r] = pv;
            rs += pv;
          }
      } else {
        for (int nk = 0; nk < 2; ++nk)
          for (int r = 0; r < 4; ++r) {
            float pv = sc[mi][nk][r];
            pv = (pv <= -1e29f) ? 0.f : __expf(pv - mnew);  // guard: mnew may be -1e30
            sc[mi][nk][r] = pv;
            rs += pv;
          }
      }
      rs += __shfl_xor(rs, 16);
      rs += __shfl_xor(rs, 32);
      const float alpha = __expf(mrun[mi] - mnew);  // exp(0)=1 when max unchanged
      mrun[mi] = mnew;
      lrun[mi] = lrun[mi] * alpha + rs;
      for (int nd = 0; nd < 8; ++nd)
        for (int r = 0; r < 4; ++r) accO[mi][nd][r] *= alpha;
      for (int nk = 0; nk < 2; ++nk) {
        u16x4 o;
        for (int r = 0; r < 4; ++r) o[r] = f2bf(sc[mi][nk][r]);
        *(u16x4*)&myPs[(mi * 16 + cc) * 40 + nk * 16 + g * 4] = o;
      }
    }

    // O^T += V^T P^T  (vb rows from swizzled Vl; pa same-wave from Ps)
    __builtin_amdgcn_s_setprio(1);
    {
      s16x8 pa[2];
      for (int mi = 0; mi < 2; ++mi)
        pa[mi] = *(const s16x8*)&myPs[(mi * 16 + cc) * 40 + g * 8];
      for (int nd = 0; nd < 8; ++nd) {
        const int d = nd * 16 + cc;
        s16x8 vb = *(const s16x8*)&Vl[cur][d * 32 + ((g ^ (d & 3)) * 8)];
        for (int mi = 0; mi < 2; ++mi)
          accO[mi][nd] = __builtin_amdgcn_mfma_f32_16x16x32_bf16(vb, pa[mi], accO[mi][nd], 0, 0, 0);
      }
    }
    __builtin_amdgcn_s_setprio(0);

    __syncthreads();   // drains stage(kt+1) vmcnt + all waves done with buf[cur]
    cur ^= 1;
  }

  // write O: q = w*32+mi*16+cc (row), d = nd*16+g*4+r (col)
  u16* op = AO + ((size_t)b * 4096 + q0) * 2048 + (size_t)h * 128;
  for (int mi = 0; mi < 2; ++mi) {
    const float inv = 1.0f / lrun[mi];
    for (int nd = 0; nd < 8; ++nd) {
      u16x4 o;
      for (int r = 0; r < 4; ++r) o[r] = f2bf(accO[mi][nd][r] * inv);
      *(u16x4*)(op + (size_t)(w * 32 + mi * 16 + cc) * 2048 + nd * 16 + g * 4) = o;
    }
  }
}

extern "C" void kernel_launch(void* const* d_in, const int* in_sizes, int n_in,
                              void* d_out, int out_size, void* d_ws, size_t ws_size,
                              hipStream_t stream) {
  const float* emb  = (const float*)d_in[0];
  const float* cosb = (const float*)d_in[1];
  const float* sinb = (const float*)d_in[2];
  const float* wq   = (const float*)d_in[3];
  const float* wk   = (const float*)d_in[4];
  const float* wv   = (const float*)d_in[5];
  const float* wo   = (const float*)d_in[6];
  float* out = (float*)d_out;

  char* ws = (char*)d_ws;
  size_t off = 0;
  auto alloc = [&](size_t bytes) -> void* {
    void* p = ws + off;
    off += (bytes + 255) & ~(size_t)255;
    return p;
  };
  u16* X   = (u16*)alloc((size_t)8192 * 2048 * 2);   // normed bf16; reused as attn_out
  u16* Wt  = (u16*)alloc((size_t)3072 * 2048 * 2);   // [wq|wk|wv] transposed [n][k]
  u16* Wot = (u16*)alloc((size_t)2048 * 2048 * 2);   // wo transposed
  u16* qkv = (u16*)alloc((size_t)8192 * 3072 * 2);   // V third unused (V goes to VtB)
  u16* Qb  = (u16*)alloc((size_t)2 * 16 * 4096 * 128 * 2);
  u16* Kb  = (u16*)alloc((size_t)2 * 4 * 4096 * 128 * 2);
  u16* VtB = (u16*)alloc((size_t)2 * 4 * 128 * 4096 * 2);  // V transposed [b][hkv][d][s]
  u16* AOb = X;  // X dead after GEMM1

  k_transpose<<<dim3(64, 64), 256, 0, stream>>>(wq, Wt, 2048, 2048);
  k_transpose<<<dim3(16, 64), 256, 0, stream>>>(wk, Wt + (size_t)2048 * 2048, 512, 2048);
  k_transpose<<<dim3(16, 64), 256, 0, stream>>>(wv, Wt + (size_t)2560 * 2048, 512, 2048);
  k_transpose<<<dim3(64, 64), 256, 0, stream>>>(wo, Wot, 2048, 2048);
  k_rmsnorm<<<8192, 256, 0, stream>>>(emb, X);
  k_gemm_bt<0><<<dim3(24, 64), 256, 0, stream>>>(X, Wt, 3072, 2048, qkv, nullptr, nullptr, VtB, 2560);
  k_rope<<<8192, 192, 0, stream>>>(qkv, cosb, sinb, Qb, Kb);
  k_attn<<<dim3(1024), 256, 0, stream>>>(Qb, Kb, VtB, AOb);
  k_gemm_bt<1><<<dim3(16, 64), 256, 0, stream>>>(AOb, Wot, 2048, 2048, nullptr, emb, out, nullptr, 1 << 30);
}

// Round 7
// 355.800 us; speedup vs baseline: 1.6804x; 1.1491x over previous
//
#include <hip/hip_runtime.h>

typedef unsigned short u16;
typedef __attribute__((ext_vector_type(8))) short s16x8;
typedef __attribute__((ext_vector_type(8))) unsigned short u16x8;
typedef __attribute__((ext_vector_type(4))) unsigned short u16x4;
typedef __attribute__((ext_vector_type(4))) float f32x4;

#define DEV __device__ __forceinline__

DEV u16 f2bf(float x) {
  union { float f; unsigned u; } c; c.f = x;
  unsigned r = c.u + 0x7FFFu + ((c.u >> 16) & 1u);
  return (u16)(r >> 16);
}
DEV float bf2f(u16 u) {
  union { unsigned u; float f; } c; c.u = ((unsigned)u) << 16;
  return c.f;
}
DEV void gload_lds16(const void* g, void* l) {
  __builtin_amdgcn_global_load_lds((const __attribute__((address_space(1))) void*)g,
                                   (__attribute__((address_space(3))) void*)l, 16, 0, 0);
}

// ---------------- RMSNorm: f32 [8192][2048] -> bf16 X ----------------
__global__ __launch_bounds__(256) void k_rmsnorm(const float* __restrict__ emb, u16* __restrict__ X) {
  const int row = blockIdx.x;
  const int t = threadIdx.x;
  const float4* p4 = (const float4*)(emb + (size_t)row * 2048);
  float4 v0 = p4[t * 2], v1 = p4[t * 2 + 1];
  float ss = v0.x * v0.x + v0.y * v0.y + v0.z * v0.z + v0.w * v0.w
           + v1.x * v1.x + v1.y * v1.y + v1.z * v1.z + v1.w * v1.w;
  for (int off = 32; off; off >>= 1) ss += __shfl_xor(ss, off);
  __shared__ float red[4];
  if ((t & 63) == 0) red[t >> 6] = ss;
  __syncthreads();
  float tot = red[0] + red[1] + red[2] + red[3];
  float inv = rsqrtf(tot * (1.0f / 2048.0f) + 1e-5f);
  float v[8] = {v0.x, v0.y, v0.z, v0.w, v1.x, v1.y, v1.z, v1.w};
  u16x8 o;
  for (int j = 0; j < 8; ++j) o[j] = f2bf(v[j] * inv);
  *(u16x8*)(X + (size_t)row * 2048 + t * 8) = o;
}

// ------------- transpose f32 [R][C] -> bf16 [C][dstStride] -------------
__global__ __launch_bounds__(256) void k_transpose(const float* __restrict__ src, u16* __restrict__ dst,
                                                   int C, int dstStride) {
  __shared__ float tile[32][33];
  const int bc = blockIdx.x * 32, br = blockIdx.y * 32;
  const int tx = threadIdx.x & 31, ty = threadIdx.x >> 5;
  for (int i = 0; i < 32; i += 8)
    tile[ty + i][tx] = src[(size_t)(br + ty + i) * C + bc + tx];
  __syncthreads();
  for (int i = 0; i < 32; i += 8)
    dst[(size_t)(bc + ty + i) * dstStride + br + tx] = f2bf(tile[tx][ty + i]);
}

// ------------- GEMM 256x256 tile, BK=64, 8 waves, phase-split pipelined -------------
// C[M][N] = A[M][K] * Bt[N][K]^T.
// LDS [256][64] bf16 per operand, double-buffered (128 KB). XOR chunk swizzle
// (chunk ^= row&7): ds_read_b128 fragment reads hit the uniform 8-lanes-per-bank-quad
// b128 floor (conflict-free); global source pre-inverse-swizzled, LDS dst linear.
// Per K-tile: 4 phases {ds-read frags; issue 2/8 prefetch gloads for t+1; s_barrier;
// setprio(1); 16 MFMA; setprio(0)}, then one __syncthreads (vmcnt drain lands ~3
// phases after prefetch issue -> cheap).
// EPI==0: bf16 C write; tiles with n0 >= vcol0 write V transposed to VtOut.
// EPI==1: f32 C write + residual add.
template <int EPI>
__global__ __launch_bounds__(512) void k_gemm256(const u16* __restrict__ A, const u16* __restrict__ Bt,
                                                 const int N, const int K, const int NBN,
                                                 u16* __restrict__ Cb, const float* __restrict__ Emb,
                                                 float* __restrict__ Cf,
                                                 u16* __restrict__ VtOut, const int vcol0) {
  __shared__ u16 Asm[2][256 * 64];
  __shared__ u16 Bsm[2][256 * 64];
  const int t = threadIdx.x, w = t >> 6, l = t & 63, g = (l >> 4), cc = l & 15;
  const int wm = w >> 2, wn = w & 3;

  const int cpx = gridDim.x >> 3;                       // grid % 8 == 0 by construction
  const int lin = (blockIdx.x & 7) * cpx + (blockIdx.x >> 3);
  const int bm = lin / NBN, bn = lin % NBN;
  const size_t m0 = (size_t)bm * 256, n0 = (size_t)bn * 256;

  const int srow = t >> 3, sch = t & 7;                 // staging: row-within-64, 16B chunk

  auto stA = [&](int kt, int p, int pass) {
    const int row = pass * 64 + srow;
    const int c2 = sch ^ (row & 7);
    gload_lds16(A + (m0 + row) * K + kt * 64 + c2 * 8, &Asm[p][row * 64 + sch * 8]);
  };
  auto stB = [&](int kt, int p, int pass) {
    const int row = pass * 64 + srow;
    const int c2 = sch ^ (row & 7);
    gload_lds16(Bt + (n0 + row) * K + kt * 64 + c2 * 8, &Bsm[p][row * 64 + sch * 8]);
  };

  f32x4 acc[8][4];
#pragma unroll
  for (int mi = 0; mi < 8; ++mi)
#pragma unroll
    for (int ni = 0; ni < 4; ++ni) acc[mi][ni] = (f32x4){0.f, 0.f, 0.f, 0.f};

  const int NT = K >> 6;
#pragma unroll
  for (int pass = 0; pass < 4; ++pass) { stA(0, 0, pass); stB(0, 0, pass); }
  __syncthreads();

  for (int kt = 0; kt < NT; ++kt) {
    const int p = kt & 1;
    const bool pf = (kt + 1 < NT);
    const u16* Ap = &Asm[p][0];
    const u16* Bp = &Bsm[p][0];

    s16x8 bf[2][4];
#pragma unroll
    for (int kk = 0; kk < 2; ++kk)
#pragma unroll
      for (int ni = 0; ni < 4; ++ni) {
        const int row = wn * 64 + ni * 16 + cc;
        bf[kk][ni] = *(const s16x8*)&Bp[row * 64 + (((kk * 4 + g) ^ (row & 7)) * 8)];
      }

#pragma unroll
    for (int q = 0; q < 4; ++q) {
      s16x8 af[2][2];
#pragma unroll
      for (int kk = 0; kk < 2; ++kk)
#pragma unroll
        for (int m2 = 0; m2 < 2; ++m2) {
          const int row = wm * 128 + (q * 2 + m2) * 16 + cc;
          af[kk][m2] = *(const s16x8*)&Ap[row * 64 + (((kk * 4 + g) ^ (row & 7)) * 8)];
        }
      if (pf) {
        if (q == 0) { stA(kt + 1, p ^ 1, 0); stA(kt + 1, p ^ 1, 1); }
        else if (q == 1) { stA(kt + 1, p ^ 1, 2); stA(kt + 1, p ^ 1, 3); }
        else if (q == 2) { stB(kt + 1, p ^ 1, 0); stB(kt + 1, p ^ 1, 1); }
        else { stB(kt + 1, p ^ 1, 2); stB(kt + 1, p ^ 1, 3); }
      }
      __builtin_amdgcn_s_barrier();
      __builtin_amdgcn_s_setprio(1);
#pragma unroll
      for (int m2 = 0; m2 < 2; ++m2)
#pragma unroll
        for (int ni = 0; ni < 4; ++ni)
#pragma unroll
          for (int kk = 0; kk < 2; ++kk)
            acc[q * 2 + m2][ni] =
                __builtin_amdgcn_mfma_f32_16x16x32_bf16(af[kk][m2], bf[kk][ni], acc[q * 2 + m2][ni], 0, 0, 0);
      __builtin_amdgcn_s_setprio(0);
    }
    __syncthreads();   // all waves done reading buf p; prefetch into p^1 drained
  }

  if (EPI == 1) {
#pragma unroll
    for (int mi = 0; mi < 8; ++mi)
#pragma unroll
      for (int ni = 0; ni < 4; ++ni)
#pragma unroll
        for (int r = 0; r < 4; ++r) {
          const size_t row = m0 + wm * 128 + mi * 16 + g * 4 + r;
          const size_t col = n0 + wn * 64 + ni * 16 + cc;
          Cf[row * N + col] = acc[mi][ni][r] + Emb[row * N + col];
        }
  } else if ((int)n0 >= vcol0) {
    const int bb = (int)(m0 >> 12);
    const int s0base = (int)(m0 & 4095);
#pragma unroll
    for (int mi = 0; mi < 8; ++mi)
#pragma unroll
      for (int ni = 0; ni < 4; ++ni) {
        const int dcol = (int)(n0 - vcol0) + wn * 64 + ni * 16 + cc;   // 0..511
        const int hkv = dcol >> 7, d = dcol & 127;
        const int s = s0base + wm * 128 + mi * 16 + g * 4;
        u16x4 o;
#pragma unroll
        for (int r = 0; r < 4; ++r) o[r] = f2bf(acc[mi][ni][r]);
        *(u16x4*)(VtOut + ((size_t)(bb * 4 + hkv) * 128 + d) * 4096 + s) = o;
      }
  } else {
#pragma unroll
    for (int mi = 0; mi < 8; ++mi)
#pragma unroll
      for (int ni = 0; ni < 4; ++ni)
#pragma unroll
        for (int r = 0; r < 4; ++r) {
          const size_t row = m0 + wm * 128 + mi * 16 + g * 4 + r;
          const size_t col = n0 + wn * 64 + ni * 16 + cc;
          Cb[row * N + col] = f2bf(acc[mi][ni][r]);
        }
  }
}

// ------------- RoPE + scatter: qkv [8192][3072] -> Q/K (V handled by GEMM1) -------------
__global__ __launch_bounds__(192) void k_rope(const u16* __restrict__ qkv, const float* __restrict__ cosb,
                                              const float* __restrict__ sinb, u16* __restrict__ Q,
                                              u16* __restrict__ K) {
  const int row = blockIdx.x;
  const int b = row >> 12, s = row & 4095;
  const int t = threadIdx.x;
  const u16* src = qkv + (size_t)row * 3072;
  if (t < 128) {
    const int h = t >> 3, d0 = (t & 7) * 8;
    const float* cp = cosb + (size_t)s * 128;
    const float* sp = sinb + (size_t)s * 128;
    u16x8 lo = *(const u16x8*)(src + h * 128 + d0);
    u16x8 hi = *(const u16x8*)(src + h * 128 + d0 + 64);
    u16x8 olo, ohi;
    for (int j = 0; j < 8; ++j) {
      float fl = bf2f(lo[j]), fh = bf2f(hi[j]);
      olo[j] = f2bf(cp[d0 + j] * fl + sp[d0 + j] * fh);
      ohi[j] = f2bf(cp[d0 + 64 + j] * fh + sp[d0 + 64 + j] * fl);
    }
    u16* dq = Q + (((size_t)b * 16 + h) * 4096 + s) * 128;
    *(u16x8*)(dq + d0) = olo;
    *(u16x8*)(dq + d0 + 64) = ohi;
  } else if (t < 160) {   // only 4 kv heads
    const int idx = t - 128, hk = idx >> 3, d0 = (idx & 7) * 8;
    const float* cp = cosb + 524288 + (size_t)s * 128;
    const float* sp = sinb + 524288 + (size_t)s * 128;
    u16x8 lo = *(const u16x8*)(src + 2048 + hk * 128 + d0);
    u16x8 hi = *(const u16x8*)(src + 2048 + hk * 128 + d0 + 64);
    u16x8 olo, ohi;
    for (int j = 0; j < 8; ++j) {
      float fl = bf2f(lo[j]), fh = bf2f(hi[j]);
      olo[j] = f2bf(cp[d0 + j] * fl + sp[d0 + j] * fh);
      ohi[j] = f2bf(cp[d0 + 64 + j] * fh + sp[d0 + 64 + j] * fl);
    }
    u16* dk = K + (((size_t)b * 4 + hk) * 4096 + s) * 128;
    *(u16x8*)(dk + d0) = olo;
    *(u16x8*)(dk + d0 + 64) = ohi;
  }
}

// ------------- sliding-window flash attention, 2-phase pipelined LDS staging -------------
__global__ __launch_bounds__(256) void k_attn(const u16* __restrict__ Q, const u16* __restrict__ K,
                                              const u16* __restrict__ Vt, u16* __restrict__ AO) {
  const int bid = blockIdx.x;
  const int lin = (bid & 7) * 128 + (bid >> 3);   // XCD-pinned: group = bid&7
  const int grp = lin >> 7;
  const int b = grp >> 2, hkv = grp & 3;
  const int rem = lin & 127;
  const int h = hkv * 4 + (rem >> 5);
  const int qt = rem & 31;

  const int t = threadIdx.x, w = t >> 6, l = t & 63, g = l >> 4, cc = l & 15;
  const int q0 = qt * 128;
  const u16* Qp = Q + (((size_t)b * 16 + h) * 4096 + q0) * 128;
  const u16* Kp = K + ((size_t)b * 4 + hkv) * 4096 * 128;
  const u16* Vp = Vt + ((size_t)b * 4 + hkv) * 128 * 4096;

  __shared__ u16 Kl[2][32 * 128];   // [key][d], swizzled chunks (^row&7)
  __shared__ u16 Vl[2][128 * 32];   // [d][key], swizzled chunks (^d&3)
  __shared__ u16 Ps[4][32 * 40];    // per-wave P, stride 40 u16
  u16* myPs = &Ps[w][0];

  auto stage = [&](int kt, int bufi) {
    for (int pass = 0; pass < 2; ++pass) {
      const int m = pass * 256 + t;
      const int row = m >> 4, cst = m & 15;
      const int cor = cst ^ (row & 7);
      gload_lds16(Kp + (size_t)(kt * 32 + row) * 128 + cor * 8, &Kl[bufi][m * 8]);
    }
    for (int pass = 0; pass < 2; ++pass) {
      const int m = pass * 256 + t;
      const int d = m >> 2, cst = m & 3;
      const int cor = cst ^ (d & 3);
      gload_lds16(Vp + (size_t)d * 4096 + kt * 32 + cor * 8, &Vl[bufi][m * 8]);
    }
  };

  s16x8 qf[2][4];
  for (int mi = 0; mi < 2; ++mi)
    for (int kk = 0; kk < 4; ++kk)
      qf[mi][kk] = *(const s16x8*)(Qp + (size_t)(w * 32 + mi * 16 + cc) * 128 + kk * 32 + g * 8);

  f32x4 accO[2][8];
  for (int mi = 0; mi < 2; ++mi)
    for (int nd = 0; nd < 8; ++nd) accO[mi][nd] = (f32x4){0.f, 0.f, 0.f, 0.f};
  float mrun[2], lrun[2];
  for (int mi = 0; mi < 2; ++mi) { mrun[mi] = -1e30f; lrun[mi] = 0.f; }

  int lo = q0 - 511; if (lo < 0) lo = 0;
  const int kt_lo = lo >> 5, kt_hi = (q0 + 127) >> 5;
  const float scale = 0.08838834764831845f;

  int cur = 0;
  stage(kt_lo, 0);
  __syncthreads();

  for (int kt = kt_lo; kt <= kt_hi; ++kt) {
    if (kt < kt_hi) stage(kt + 1, cur ^ 1);

    f32x4 sc[2][2];
    for (int mi = 0; mi < 2; ++mi)
      for (int nk = 0; nk < 2; ++nk) sc[mi][nk] = (f32x4){0.f, 0.f, 0.f, 0.f};
    __builtin_amdgcn_s_setprio(1);
    for (int kk = 0; kk < 4; ++kk) {
      s16x8 kb[2];
      for (int nk = 0; nk < 2; ++nk) {
        const int row = nk * 16 + cc;
        kb[nk] = *(const s16x8*)&Kl[cur][row * 128 + (((kk * 4 + g) ^ (row & 7)) * 8)];
      }
      for (int mi = 0; mi < 2; ++mi)
        for (int nk = 0; nk < 2; ++nk)
          sc[mi][nk] = __builtin_amdgcn_mfma_f32_16x16x32_bf16(kb[nk], qf[mi][kk], sc[mi][nk], 0, 0, 0);
    }
    __builtin_amdgcn_s_setprio(0);

    const bool full = (kt * 32 >= q0 - 384) && (kt * 32 + 31 <= q0);

    for (int mi = 0; mi < 2; ++mi) {
      const int qpos = q0 + w * 32 + mi * 16 + cc;
      if (full) {
        for (int nk = 0; nk < 2; ++nk)
          for (int r = 0; r < 4; ++r) sc[mi][nk][r] *= scale;
      } else {
        for (int nk = 0; nk < 2; ++nk)
          for (int r = 0; r < 4; ++r) {
            const int kpos = kt * 32 + nk * 16 + g * 4 + r;
            const float v = sc[mi][nk][r] * scale;
            sc[mi][nk][r] = (kpos <= qpos && kpos + 512 > qpos) ? v : -1e30f;
          }
      }
      float rm = sc[mi][0][0];
      for (int nk = 0; nk < 2; ++nk)
        for (int r = 0; r < 4; ++r) rm = fmaxf(rm, sc[mi][nk][r]);
      rm = fmaxf(rm, __shfl_xor(rm, 16));
      rm = fmaxf(rm, __shfl_xor(rm, 32));
      const float mnew = fmaxf(mrun[mi], rm);
      float rs = 0.f;
      if (full) {
        for (int nk = 0; nk < 2; ++nk)
          for (int r = 0; r < 4; ++r) {
            float pv = __expf(sc[mi][nk][r] - mnew);
            sc[mi][nk][r] = pv;
            rs += pv;
          }
      } else {
        for (int nk = 0; nk < 2; ++nk)
          for (int r = 0; r < 4; ++r) {
            float pv = sc[mi][nk][r];
            pv = (pv <= -1e29f) ? 0.f : __expf(pv - mnew);
            sc[mi][nk][r] = pv;
            rs += pv;
          }
      }
      rs += __shfl_xor(rs, 16);
      rs += __shfl_xor(rs, 32);
      const float alpha = __expf(mrun[mi] - mnew);
      mrun[mi] = mnew;
      lrun[mi] = lrun[mi] * alpha + rs;
      for (int nd = 0; nd < 8; ++nd)
        for (int r = 0; r < 4; ++r) accO[mi][nd][r] *= alpha;
      for (int nk = 0; nk < 2; ++nk) {
        u16x4 o;
        for (int r = 0; r < 4; ++r) o[r] = f2bf(sc[mi][nk][r]);
        *(u16x4*)&myPs[(mi * 16 + cc) * 40 + nk * 16 + g * 4] = o;
      }
    }

    __builtin_amdgcn_s_setprio(1);
    {
      s16x8 pa[2];
      for (int mi = 0; mi < 2; ++mi)
        pa[mi] = *(const s16x8*)&myPs[(mi * 16 + cc) * 40 + g * 8];
      for (int nd = 0; nd < 8; ++nd) {
        const int d = nd * 16 + cc;
        s16x8 vb = *(const s16x8*)&Vl[cur][d * 32 + ((g ^ (d & 3)) * 8)];
        for (int mi = 0; mi < 2; ++mi)
          accO[mi][nd] = __builtin_amdgcn_mfma_f32_16x16x32_bf16(vb, pa[mi], accO[mi][nd], 0, 0, 0);
      }
    }
    __builtin_amdgcn_s_setprio(0);

    __syncthreads();
    cur ^= 1;
  }

  u16* op = AO + ((size_t)b * 4096 + q0) * 2048 + (size_t)h * 128;
  for (int mi = 0; mi < 2; ++mi) {
    const float inv = 1.0f / lrun[mi];
    for (int nd = 0; nd < 8; ++nd) {
      u16x4 o;
      for (int r = 0; r < 4; ++r) o[r] = f2bf(accO[mi][nd][r] * inv);
      *(u16x4*)(op + (size_t)(w * 32 + mi * 16 + cc) * 2048 + nd * 16 + g * 4) = o;
    }
  }
}

extern "C" void kernel_launch(void* const* d_in, const int* in_sizes, int n_in,
                              void* d_out, int out_size, void* d_ws, size_t ws_size,
                              hipStream_t stream) {
  const float* emb  = (const float*)d_in[0];
  const float* cosb = (const float*)d_in[1];
  const float* sinb = (const float*)d_in[2];
  const float* wq   = (const float*)d_in[3];
  const float* wk   = (const float*)d_in[4];
  const float* wv   = (const float*)d_in[5];
  const float* wo   = (const float*)d_in[6];
  float* out = (float*)d_out;

  char* ws = (char*)d_ws;
  size_t off = 0;
  auto alloc = [&](size_t bytes) -> void* {
    void* p = ws + off;
    off += (bytes + 255) & ~(size_t)255;
    return p;
  };
  u16* X   = (u16*)alloc((size_t)8192 * 2048 * 2);   // normed bf16; reused as attn_out
  u16* Wt  = (u16*)alloc((size_t)3072 * 2048 * 2);   // [wq|wk|wv] transposed [n][k]
  u16* Wot = (u16*)alloc((size_t)2048 * 2048 * 2);   // wo transposed
  u16* qkv = (u16*)alloc((size_t)8192 * 3072 * 2);   // V third unused (V goes to VtB)
  u16* Qb  = (u16*)alloc((size_t)2 * 16 * 4096 * 128 * 2);
  u16* Kb  = (u16*)alloc((size_t)2 * 4 * 4096 * 128 * 2);
  u16* VtB = (u16*)alloc((size_t)2 * 4 * 128 * 4096 * 2);  // V transposed [b][hkv][d][s]
  u16* AOb = X;  // X dead after GEMM1

  k_transpose<<<dim3(64, 64), 256, 0, stream>>>(wq, Wt, 2048, 2048);
  k_transpose<<<dim3(16, 64), 256, 0, stream>>>(wk, Wt + (size_t)2048 * 2048, 512, 2048);
  k_transpose<<<dim3(16, 64), 256, 0, stream>>>(wv, Wt + (size_t)2560 * 2048, 512, 2048);
  k_transpose<<<dim3(64, 64), 256, 0, stream>>>(wo, Wot, 2048, 2048);
  k_rmsnorm<<<8192, 256, 0, stream>>>(emb, X);
  // GEMM1: 8192x3072x2048, 256^2 tiles -> grid 12*32=384 (384%8==0)
  k_gemm256<0><<<dim3(384), 512, 0, stream>>>(X, Wt, 3072, 2048, 12, qkv, nullptr, nullptr, VtB, 2560);
  k_rope<<<8192, 192, 0, stream>>>(qkv, cosb, sinb, Qb, Kb);
  k_attn<<<dim3(1024), 256, 0, stream>>>(Qb, Kb, VtB, AOb);
  // GEMM2: 8192x2048x2048 -> grid 8*32=256
  k_gemm256<1><<<dim3(256), 512, 0, stream>>>(AOb, Wot, 2048, 2048, 8, nullptr, emb, out, nullptr, 1 << 30);
}